// Round 1
// baseline (156.749 us; speedup 1.0000x reference)
//
#include <hip/hip_runtime.h>
#include <math.h>

// Problem constants (from setup_inputs)
#define NN 2
#define LL 2304          // 48*48
#define CC 384
#define KK 16
#define DINO_SHIFT 0.7f

// Tiling
#define BT 128           // pair-tile edge (s and l)
#define CH 16            // C-chunk staged in LDS
#define CHP 20           // padded LDS row stride (floats): 80 B, 16B-aligned, conflict-free
#define NTILE 18         // LL / BT
#define NBLK (NN * NTILE * NTILE)   // 648 blocks

// ---------------------------------------------------------------------------
// Kernel 1: per row r in [0, N*L): rnorm = 1/max(||f_r||,eps), P = exp(p_r),
// selfdot_r = sum_k P*p  (one 64-lane wave per row)
// ---------------------------------------------------------------------------
__global__ void prep_kernel(const float* __restrict__ f,
                            const float* __restrict__ p,
                            float* __restrict__ rnorm,
                            float* __restrict__ Pexp,
                            float* __restrict__ selfdot) {
    const int r = blockIdx.x;          // 0 .. NN*LL-1
    const int lane = threadIdx.x;      // 0 .. 63
    const float* frow = f + (size_t)r * CC;
    float ss = 0.f;
#pragma unroll
    for (int i = 0; i < CC / 64; ++i) {
        float v = frow[lane + 64 * i];
        ss = fmaf(v, v, ss);
    }
#pragma unroll
    for (int off = 32; off > 0; off >>= 1) ss += __shfl_down(ss, off);
    if (lane == 0) rnorm[r] = 1.0f / fmaxf(sqrtf(ss), 1e-12f);

    if (lane < KK) {
        float pv = p[(size_t)r * KK + lane];
        float e = expf(pv);
        Pexp[(size_t)r * KK + lane] = e;
        float sd = e * pv;
#pragma unroll
        for (int off = 8; off > 0; off >>= 1) sd += __shfl_down(sd, off, 16);
        if (lane == 0) selfdot[r] = sd;
    }
}

// ---------------------------------------------------------------------------
// Kernel 2: fused pairwise tile kernel.
// Block = 128x128 (s,l) pairs, 256 threads as 16x16, 8x8 pairs per thread.
//  - f-dot over C=384 via LDS-staged 16-wide chunks, register-blocked FMA.
//  - p-part (KL) fused at the end from LDS-staged P (s-rows) and p (l-rows).
//  - per-block partial {pos_sum, neg_sum, n_pos, n_neg} -> partials[b][4].
// ---------------------------------------------------------------------------
__global__ __launch_bounds__(256, 2) void pair_kernel(
    const float* __restrict__ f,
    const float* __restrict__ p,
    const float* __restrict__ rnorm,
    const float* __restrict__ Pexp,
    const float* __restrict__ selfdot,
    float* __restrict__ partials)
{
    __shared__ float fs[BT][CHP];
    __shared__ float fl[BT][CHP];
    __shared__ float red[4][4];

    const int b = blockIdx.x;
    const int n = b / (NTILE * NTILE);
    const int t = b % (NTILE * NTILE);
    const int s0 = (t / NTILE) * BT;
    const int l0 = (t % NTILE) * BT;

    const int tid = threadIdx.x;
    const int tx = tid & 15;
    const int ty = tid >> 4;

    float acc[8][8];
#pragma unroll
    for (int i = 0; i < 8; ++i)
#pragma unroll
        for (int j = 0; j < 8; ++j) acc[i][j] = 0.f;

    const float* fb = f + (size_t)n * LL * CC;
    const int rowA = tid >> 2;         // 0..63
    const int qA = (tid & 3) * 4;      // 0,4,8,12

    for (int c0 = 0; c0 < CC; c0 += CH) {
        __syncthreads();               // protect previous chunk's reads
#pragma unroll
        for (int pass = 0; pass < 2; ++pass) {
            const int row = rowA + 64 * pass;
            float4 vs = *(const float4*)(fb + (size_t)(s0 + row) * CC + c0 + qA);
            float4 vl = *(const float4*)(fb + (size_t)(l0 + row) * CC + c0 + qA);
            *(float4*)&fs[row][qA] = vs;
            *(float4*)&fl[row][qA] = vl;
        }
        __syncthreads();
#pragma unroll
        for (int c = 0; c < CH; ++c) {
            float rs[8], rl[8];
#pragma unroll
            for (int i = 0; i < 8; ++i) rs[i] = fs[ty + 16 * i][c];
#pragma unroll
            for (int j = 0; j < 8; ++j) rl[j] = fl[tx + 16 * j][c];
#pragma unroll
            for (int i = 0; i < 8; ++i)
#pragma unroll
                for (int j = 0; j < 8; ++j)
                    acc[i][j] = fmaf(rs[i], rl[j], acc[i][j]);
        }
    }

    // Stage Pexp for s-rows into fs, raw log-p for l-rows into fl (128x16 each)
    __syncthreads();
    {
        const int row = tid >> 1;          // 0..127
        const int q = (tid & 1) * 8;       // 0 or 8
        const float* Pb = Pexp + ((size_t)n * LL + s0 + row) * KK + q;
        const float* pb = p    + ((size_t)n * LL + l0 + row) * KK + q;
        *(float4*)&fs[row][q]     = *(const float4*)Pb;
        *(float4*)&fs[row][q + 4] = *(const float4*)(Pb + 4);
        *(float4*)&fl[row][q]     = *(const float4*)pb;
        *(float4*)&fl[row][q + 4] = *(const float4*)(pb + 4);
    }
    __syncthreads();

    float rnl[8];
#pragma unroll
    for (int j = 0; j < 8; ++j)
        rnl[j] = rnorm[(size_t)n * LL + l0 + tx + 16 * j];

    float pos = 0.f, neg = 0.f;
    int np = 0, nn = 0;
#pragma unroll
    for (int i = 0; i < 8; ++i) {
        const int sy = ty + 16 * i;
        float Pr[KK];
#pragma unroll
        for (int k = 0; k < KK; ++k) Pr[k] = fs[sy][k];
        const float rns = rnorm[(size_t)n * LL + s0 + sy];
        const float sf  = selfdot[(size_t)n * LL + s0 + sy];
#pragma unroll
        for (int j = 0; j < 8; ++j) {
            const int lx = tx + 16 * j;
            float pdot = 0.f;
#pragma unroll
            for (int k = 0; k < KK; ++k) pdot = fmaf(Pr[k], fl[lx][k], pdot);
            const float fc = rns * rnl[j] * acc[i][j] - DINO_SHIFT;
            const float pc = sf - pdot;
            if (fc > 0.f)      { pos += fc * pc; ++np; }
            else if (fc < 0.f) { neg += fc * pc; ++nn; }
        }
    }

    float npf = (float)np, nnf = (float)nn;
#pragma unroll
    for (int off = 32; off > 0; off >>= 1) {
        pos += __shfl_down(pos, off);
        neg += __shfl_down(neg, off);
        npf += __shfl_down(npf, off);
        nnf += __shfl_down(nnf, off);
    }
    const int wid = tid >> 6, lane = tid & 63;
    if (lane == 0) { red[wid][0] = pos; red[wid][1] = neg; red[wid][2] = npf; red[wid][3] = nnf; }
    __syncthreads();
    if (tid == 0) {
        partials[b * 4 + 0] = red[0][0] + red[1][0] + red[2][0] + red[3][0];
        partials[b * 4 + 1] = red[0][1] + red[1][1] + red[2][1] + red[3][1];
        partials[b * 4 + 2] = red[0][2] + red[1][2] + red[2][2] + red[3][2];
        partials[b * 4 + 3] = red[0][3] + red[1][3] + red[2][3] + red[3][3];
    }
}

// ---------------------------------------------------------------------------
// Kernel 3: deterministic final reduce of 648 block partials -> loss scalar
// ---------------------------------------------------------------------------
__global__ void final_kernel(const float* __restrict__ partials,
                             const float* __restrict__ pw,
                             const float* __restrict__ nw,
                             float* __restrict__ out) {
    __shared__ float red[4][4];
    const int tid = threadIdx.x;
    float pos = 0.f, neg = 0.f, np = 0.f, nn = 0.f;
    for (int i = tid; i < NBLK; i += 256) {
        pos += partials[i * 4 + 0];
        neg += partials[i * 4 + 1];
        np  += partials[i * 4 + 2];
        nn  += partials[i * 4 + 3];
    }
#pragma unroll
    for (int off = 32; off > 0; off >>= 1) {
        pos += __shfl_down(pos, off);
        neg += __shfl_down(neg, off);
        np  += __shfl_down(np, off);
        nn  += __shfl_down(nn, off);
    }
    const int wid = tid >> 6, lane = tid & 63;
    if (lane == 0) { red[wid][0] = pos; red[wid][1] = neg; red[wid][2] = np; red[wid][3] = nn; }
    __syncthreads();
    if (tid == 0) {
        pos = red[0][0] + red[1][0] + red[2][0] + red[3][0];
        neg = red[0][1] + red[1][1] + red[2][1] + red[3][1];
        np  = red[0][2] + red[1][2] + red[2][2] + red[3][2];
        nn  = red[0][3] + red[1][3] + red[2][3] + red[3][3];
        out[0] = (pos / np) * pw[0] + (neg / nn) * nw[0];
    }
}

extern "C" void kernel_launch(void* const* d_in, const int* in_sizes, int n_in,
                              void* d_out, int out_size, void* d_ws, size_t ws_size,
                              hipStream_t stream) {
    const float* f  = (const float*)d_in[0];   // [N,H,W,C] fp32
    const float* p  = (const float*)d_in[1];   // [N,H,W,K] fp32 log-probs
    const float* pw = (const float*)d_in[2];   // [1]
    const float* nw = (const float*)d_in[3];   // [1]
    float* out = (float*)d_out;

    // Workspace layout (floats): rnorm[N*L] | selfdot[N*L] | Pexp[N*L*K] | partials[NBLK*4]
    float* rnorm    = (float*)d_ws;
    float* selfdot  = rnorm + (size_t)NN * LL;
    float* Pexp     = selfdot + (size_t)NN * LL;
    float* partials = Pexp + (size_t)NN * LL * KK;

    prep_kernel<<<NN * LL, 64, 0, stream>>>(f, p, rnorm, Pexp, selfdot);
    pair_kernel<<<NBLK, 256, 0, stream>>>(f, p, rnorm, Pexp, selfdot, partials);
    final_kernel<<<1, 256, 0, stream>>>(partials, pw, nw, out);
}

// Round 2
// 42.887 us; speedup vs baseline: 3.6549x; 3.6549x over previous
//
#include <hip/hip_runtime.h>
#include <math.h>
#include <stdint.h>

// Problem constants
#define NN 2
#define LL 2304          // 48*48
#define CC 384
#define KK 16
#define DINO_SHIFT 0.7f

// Tiling
#define BT 128
#define NTILE 18         // LL / BT
#define NBLK (NN * NTILE * NTILE)   // 648

typedef __attribute__((ext_vector_type(8))) short short8;   // 8 bf16 (4 VGPR)
typedef __attribute__((ext_vector_type(4))) float f32x4;
typedef __attribute__((ext_vector_type(4))) unsigned int u32x4;

__device__ __forceinline__ unsigned short f2bf(float x) {
    union { float f; uint32_t u; } v; v.f = x;
    uint32_t r = v.u + 0x7fffu + ((v.u >> 16) & 1u);   // RNE
    return (unsigned short)(r >> 16);
}
__device__ __forceinline__ unsigned int pk2(float a, float b) {
    return (unsigned int)f2bf(a) | ((unsigned int)f2bf(b) << 16);
}

// ---------------------------------------------------------------------------
// Kernel 1: per row r: rnorm = 1/max(||f_r||,eps); bf16-padded Pexp/plog rows
// (32 entries, upper 16 zero, for the K=32 MFMA step); selfdot = sum P*p.
// ---------------------------------------------------------------------------
__global__ void prep_kernel(const float* __restrict__ f, const float* __restrict__ p,
                            float* __restrict__ rnorm, unsigned short* __restrict__ Ppad,
                            unsigned short* __restrict__ ppad, float* __restrict__ selfdot) {
    const int r = blockIdx.x * 4 + (threadIdx.x >> 6);
    const int lane = threadIdx.x & 63;
    const float* frow = f + (size_t)r * CC;
    float ss = 0.f;
#pragma unroll
    for (int i = 0; i < CC / 64; ++i) { float v = frow[lane + 64 * i]; ss = fmaf(v, v, ss); }
#pragma unroll
    for (int off = 32; off; off >>= 1) ss += __shfl_xor(ss, off);
    if (lane == 0) rnorm[r] = 1.0f / fmaxf(sqrtf(ss), 1e-12f);

    if (lane < 32) {
        float pv = 0.f, e = 0.f;
        if (lane < KK) { pv = p[(size_t)r * KK + lane]; e = expf(pv); }
        Ppad[(size_t)r * 32 + lane] = (lane < KK) ? f2bf(e)  : (unsigned short)0;
        ppad[(size_t)r * 32 + lane] = (lane < KK) ? f2bf(pv) : (unsigned short)0;
        float sd = e * pv;
#pragma unroll
        for (int off = 8; off; off >>= 1) sd += __shfl_xor(sd, off, 16);
        if (lane == 0) selfdot[r] = sd;
    }
}

// ---------------------------------------------------------------------------
// Kernel 2: 128x128 pair tile. 4 waves (2x2), per-wave 64x64 = 4x4 frags of
// mfma_f32_16x16x32_bf16. Main loop: normalized-bf16 f tiles, XOR-swizzled
// LDS (chunk ^= row&7 kills the 128B-row bank conflict). Epilogue: pdot tile
// via one zero-padded MFMA k-step, then classify/accumulate.
// ---------------------------------------------------------------------------
__global__ __launch_bounds__(256, 2) void pair_kernel(
    const float* __restrict__ f, const float* __restrict__ rnorm,
    const unsigned short* __restrict__ Ppad, const unsigned short* __restrict__ ppad,
    const float* __restrict__ selfdot, float* __restrict__ partials)
{
    __shared__ char lds[33280] __attribute__((aligned(16)));
    char* ldsA = lds;              // 16KB f-tile (s rows); later P tile [0,8K) + p tile [8K,16K)
    char* ldsB = lds + 16384;      // 16KB f-tile (l rows); later selfdot (512B)
    __shared__ float red[4][4];

    const int b = blockIdx.x;
    const int n = b / (NTILE * NTILE);
    const int t = b % (NTILE * NTILE);
    const int s0 = (t / NTILE) * BT;
    const int l0 = (t % NTILE) * BT;

    const int tid = threadIdx.x;
    const int lane = tid & 63;
    const int w = tid >> 6;
    const int wrow = w >> 1, wcol = w & 1;       // 2x2 wave grid, 64x64 per wave

    const float* fb = f + (size_t)n * LL * CC;
    const float* rnb = rnorm + (size_t)n * LL;

    // staging geometry fixed per thread: slot = tid + 256*i -> (row, chunk j)
    float rnA[4], rnB[4];
#pragma unroll
    for (int i = 0; i < 4; ++i) {
        int row = (tid + 256 * i) >> 3;
        rnA[i] = rnb[s0 + row];
        rnB[i] = rnb[l0 + row];
    }

    f32x4 acc[4][4] = {};

    for (int c0 = 0; c0 < CC; c0 += 64) {
        __syncthreads();
#pragma unroll
        for (int i = 0; i < 4; ++i) {
            const int slot = tid + 256 * i;
            const int row = slot >> 3, j = slot & 7;
            const int dst = row * 128 + ((j ^ (row & 7)) << 4);
            {   // A side (s rows)
                const float* src = fb + (size_t)(s0 + row) * CC + c0 + j * 8;
                f32x4 v0 = *(const f32x4*)src;
                f32x4 v1 = *(const f32x4*)(src + 4);
                u32x4 wv;
                wv[0] = pk2(v0[0] * rnA[i], v0[1] * rnA[i]);
                wv[1] = pk2(v0[2] * rnA[i], v0[3] * rnA[i]);
                wv[2] = pk2(v1[0] * rnA[i], v1[1] * rnA[i]);
                wv[3] = pk2(v1[2] * rnA[i], v1[3] * rnA[i]);
                *(u32x4*)(ldsA + dst) = wv;
            }
            {   // B side (l rows)
                const float* src = fb + (size_t)(l0 + row) * CC + c0 + j * 8;
                f32x4 v0 = *(const f32x4*)src;
                f32x4 v1 = *(const f32x4*)(src + 4);
                u32x4 wv;
                wv[0] = pk2(v0[0] * rnB[i], v0[1] * rnB[i]);
                wv[1] = pk2(v0[2] * rnB[i], v0[3] * rnB[i]);
                wv[2] = pk2(v1[0] * rnB[i], v1[1] * rnB[i]);
                wv[3] = pk2(v1[2] * rnB[i], v1[3] * rnB[i]);
                *(u32x4*)(ldsB + dst) = wv;
            }
        }
        __syncthreads();
#pragma unroll
        for (int ks = 0; ks < 2; ++ks) {
            short8 a[4], bb[4];
#pragma unroll
            for (int im = 0; im < 4; ++im) {
                const int row = wrow * 64 + im * 16 + (lane & 15);
                a[im] = *(const short8*)(ldsA + row * 128 + (((ks * 4 + (lane >> 4)) ^ (row & 7)) << 4));
            }
#pragma unroll
            for (int jn = 0; jn < 4; ++jn) {
                const int row = wcol * 64 + jn * 16 + (lane & 15);
                bb[jn] = *(const short8*)(ldsB + row * 128 + (((ks * 4 + (lane >> 4)) ^ (row & 7)) << 4));
            }
#pragma unroll
            for (int im = 0; im < 4; ++im)
#pragma unroll
                for (int jn = 0; jn < 4; ++jn)
                    acc[im][jn] = __builtin_amdgcn_mfma_f32_16x16x32_bf16(a[im], bb[jn], acc[im][jn], 0, 0, 0);
        }
    }

    // ---- epilogue staging: P (s rows) and p (l rows), 64B rows, swizzle row&3
    __syncthreads();
#pragma unroll
    for (int i = 0; i < 2; ++i) {
        const int slot = tid + 256 * i;
        const int row = slot >> 2, c = slot & 3;
        const int dst = row * 64 + ((c ^ (row & 3)) << 4);
        *(u32x4*)(ldsA + dst) =
            *(const u32x4*)((const char*)Ppad + ((size_t)(n * LL + s0 + row)) * 64 + c * 16);
        *(u32x4*)(ldsA + 8192 + dst) =
            *(const u32x4*)((const char*)ppad + ((size_t)(n * LL + l0 + row)) * 64 + c * 16);
    }
    if (tid < 128) *(float*)(ldsB + tid * 4) = selfdot[n * LL + s0 + tid];
    __syncthreads();

    short8 a2[4], b2[4];
#pragma unroll
    for (int im = 0; im < 4; ++im) {
        const int row = wrow * 64 + im * 16 + (lane & 15);
        a2[im] = *(const short8*)(ldsA + row * 64 + (((lane >> 4) ^ (row & 3)) << 4));
    }
#pragma unroll
    for (int jn = 0; jn < 4; ++jn) {
        const int row = wcol * 64 + jn * 16 + (lane & 15);
        b2[jn] = *(const short8*)(ldsA + 8192 + row * 64 + (((lane >> 4) ^ (row & 3)) << 4));
    }

    float pos = 0.f, neg = 0.f, npc = 0.f, nnc = 0.f;
#pragma unroll
    for (int im = 0; im < 4; ++im) {
        const f32x4 sd4 = *(const f32x4*)(ldsB + (wrow * 64 + im * 16 + (lane >> 4) * 4) * 4);
#pragma unroll
        for (int jn = 0; jn < 4; ++jn) {
            f32x4 z = {0.f, 0.f, 0.f, 0.f};
            f32x4 pdv = __builtin_amdgcn_mfma_f32_16x16x32_bf16(a2[im], b2[jn], z, 0, 0, 0);
#pragma unroll
            for (int r = 0; r < 4; ++r) {
                const float fc = acc[im][jn][r] - DINO_SHIFT;
                const float pc = sd4[r] - pdv[r];
                const float v = fc * pc;
                if (fc > 0.f)      { pos += v; npc += 1.f; }
                else if (fc < 0.f) { neg += v; nnc += 1.f; }
            }
        }
    }

#pragma unroll
    for (int off = 32; off; off >>= 1) {
        pos += __shfl_xor(pos, off); neg += __shfl_xor(neg, off);
        npc += __shfl_xor(npc, off); nnc += __shfl_xor(nnc, off);
    }
    if (lane == 0) { red[w][0] = pos; red[w][1] = neg; red[w][2] = npc; red[w][3] = nnc; }
    __syncthreads();
    if (tid == 0) {
        partials[b * 4 + 0] = red[0][0] + red[1][0] + red[2][0] + red[3][0];
        partials[b * 4 + 1] = red[0][1] + red[1][1] + red[2][1] + red[3][1];
        partials[b * 4 + 2] = red[0][2] + red[1][2] + red[2][2] + red[3][2];
        partials[b * 4 + 3] = red[0][3] + red[1][3] + red[2][3] + red[3][3];
    }
}

// ---------------------------------------------------------------------------
// Kernel 3: deterministic final reduce
// ---------------------------------------------------------------------------
__global__ void final_kernel(const float* __restrict__ partials,
                             const float* __restrict__ pw,
                             const float* __restrict__ nw,
                             float* __restrict__ out) {
    __shared__ float red[4][4];
    const int tid = threadIdx.x;
    float pos = 0.f, neg = 0.f, np = 0.f, nn = 0.f;
    for (int i = tid; i < NBLK; i += 256) {
        pos += partials[i * 4 + 0];
        neg += partials[i * 4 + 1];
        np  += partials[i * 4 + 2];
        nn  += partials[i * 4 + 3];
    }
#pragma unroll
    for (int off = 32; off; off >>= 1) {
        pos += __shfl_xor(pos, off); neg += __shfl_xor(neg, off);
        np  += __shfl_xor(np, off);  nn  += __shfl_xor(nn, off);
    }
    const int w = tid >> 6, lane = tid & 63;
    if (lane == 0) { red[w][0] = pos; red[w][1] = neg; red[w][2] = np; red[w][3] = nn; }
    __syncthreads();
    if (tid == 0) {
        pos = red[0][0] + red[1][0] + red[2][0] + red[3][0];
        neg = red[0][1] + red[1][1] + red[2][1] + red[3][1];
        np  = red[0][2] + red[1][2] + red[2][2] + red[3][2];
        nn  = red[0][3] + red[1][3] + red[2][3] + red[3][3];
        out[0] = (pos / np) * pw[0] + (neg / nn) * nw[0];
    }
}

extern "C" void kernel_launch(void* const* d_in, const int* in_sizes, int n_in,
                              void* d_out, int out_size, void* d_ws, size_t ws_size,
                              hipStream_t stream) {
    const float* f  = (const float*)d_in[0];
    const float* p  = (const float*)d_in[1];
    const float* pw = (const float*)d_in[2];
    const float* nw = (const float*)d_in[3];
    float* out = (float*)d_out;

    // ws layout (16B-aligned blocks):
    float* rnorm   = (float*)d_ws;                       // 4608
    float* selfdot = rnorm + (size_t)NN * LL;            // 4608
    unsigned short* Ppad = (unsigned short*)(selfdot + (size_t)NN * LL);  // 4608*32
    unsigned short* ppad = Ppad + (size_t)NN * LL * 32;                   // 4608*32
    float* partials = (float*)(ppad + (size_t)NN * LL * 32);              // 648*4

    prep_kernel<<<(NN * LL) / 4, 256, 0, stream>>>(f, p, rnorm, Ppad, ppad, selfdot);
    pair_kernel<<<NBLK, 256, 0, stream>>>(f, rnorm, Ppad, ppad, selfdot, partials);
    final_kernel<<<1, 256, 0, stream>>>(partials, pw, nw, out);
}

// Round 3
// 25.048 us; speedup vs baseline: 6.2579x; 1.7122x over previous
//
#include <hip/hip_runtime.h>
#include <math.h>
#include <stdint.h>

// Problem constants
#define NN 2
#define LL 2304          // 48*48
#define CC 384
#define KK 16
#define DINO_SHIFT 0.7f

// Tiling: 96x96 pair tiles over the (s<=l) triangle
#define NT 24                      // LL / 96
#define TB 96
#define TT ((NT * (NT + 1)) / 2)   // 300 tiles per batch
#define NBLK2 (NN * TT)            // 600 blocks

typedef __attribute__((ext_vector_type(8))) short short8;   // 8 bf16
typedef __attribute__((ext_vector_type(4))) float f32x4;

#define AS_G __attribute__((address_space(1)))
#define AS_L __attribute__((address_space(3)))

__device__ __forceinline__ unsigned short f2bf(float x) {
    union { float f; uint32_t u; } v; v.f = x;
    uint32_t r = v.u + 0x7fffu + ((v.u >> 16) & 1u);   // RNE
    return (unsigned short)(r >> 16);
}

__device__ __forceinline__ void gll16(const void* g, void* l) {
    // async global->LDS, 16B per lane; LDS dest wave-uniform base + lane*16
    __builtin_amdgcn_global_load_lds((const AS_G unsigned int*)g,
                                     (AS_L unsigned int*)l, 16, 0, 0);
}

// ---------------------------------------------------------------------------
// Kernel 1: per row r: fnorm = bf16(f_r / max(||f_r||,eps));
// Ppad/ppad = bf16 exp(p)/p padded to 32 (upper 16 zero); selfdot = sum P*p.
// One 64-lane wave per row, 4 rows per block.
// ---------------------------------------------------------------------------
__global__ void prep_kernel(const float* __restrict__ f, const float* __restrict__ p,
                            unsigned short* __restrict__ fnorm,
                            unsigned short* __restrict__ Ppad,
                            unsigned short* __restrict__ ppad,
                            float* __restrict__ selfdot) {
    const int r = blockIdx.x * 4 + (threadIdx.x >> 6);
    const int lane = threadIdx.x & 63;
    const float* frow = f + (size_t)r * CC;
    float v[6], ss = 0.f;
#pragma unroll
    for (int k = 0; k < 6; ++k) { v[k] = frow[lane + 64 * k]; ss = fmaf(v[k], v[k], ss); }
#pragma unroll
    for (int off = 32; off; off >>= 1) ss += __shfl_xor(ss, off);
    const float rn = 1.0f / fmaxf(sqrtf(ss), 1e-12f);
    unsigned short* fnr = fnorm + (size_t)r * CC;
#pragma unroll
    for (int k = 0; k < 6; ++k) fnr[lane + 64 * k] = f2bf(v[k] * rn);

    if (lane < 32) {
        float pv = 0.f, e = 0.f;
        if (lane < KK) { pv = p[(size_t)r * KK + lane]; e = expf(pv); }
        Ppad[(size_t)r * 32 + lane] = (lane < KK) ? f2bf(e)  : (unsigned short)0;
        ppad[(size_t)r * 32 + lane] = (lane < KK) ? f2bf(pv) : (unsigned short)0;
        float sd = e * pv;
#pragma unroll
        for (int off = 8; off; off >>= 1) sd += __shfl_xor(sd, off, 16);
        if (lane == 0) selfdot[r] = sd;
    }
}

// ---------------------------------------------------------------------------
// Kernel 2: 96x96 triangular pair tile (weight 2 off-diagonal).
// 4 waves (2x2), per-wave 48x48 = 3x3 frags of mfma_f32_16x16x32_bf16.
// global_load_lds staging (pre-swizzled source -> linear LDS -> swizzled read),
// 2-phase double buffer: issue STAGE(t+1) before MFMA(t), one barrier/iter.
// Diagonal tiles stage only one side.
// ---------------------------------------------------------------------------
__global__ __launch_bounds__(256, 2) void pair_kernel(
    const unsigned short* __restrict__ fnorm,
    const unsigned short* __restrict__ Ppad, const unsigned short* __restrict__ ppad,
    const float* __restrict__ selfdot, float* __restrict__ partials)
{
    __shared__ char lds[49152] __attribute__((aligned(16)));  // [2 buf][2 side][12KB]
    __shared__ float red[4][4];

    const int b = blockIdx.x;
    const int n = b / TT;
    int t = b % TT;
    int i = 0;
    while (t >= NT - i) { t -= NT - i; ++i; }
    const int j = i + t;
    const int s0 = i * TB, l0 = j * TB;
    const bool diag = (i == j);
    const float wgt = diag ? 1.f : 2.f;

    const int tid = threadIdx.x, lane = tid & 63, w = tid >> 6;
    const int wrow = w >> 1, wcol = w & 1;

    const unsigned short* fn = fnorm + (size_t)n * LL * CC;
    const int srow8 = lane >> 3, sch = lane & 7;   // staging geometry

    f32x4 acc[3][3] = {};

    auto stageF = [&](int buf, int c0) {
        char* base = lds + buf * 24576;
#pragma unroll
        for (int q = 0; q < 3; ++q) {
            const int r0 = w * 24 + q * 8;
            const int row = r0 + srow8;
            const char* src = (const char*)(fn + (size_t)(s0 + row) * CC) + c0 * 2
                              + ((sch ^ (row & 7)) << 4);
            gll16(src, base + r0 * 128);
        }
        if (!diag) {
#pragma unroll
            for (int q = 0; q < 3; ++q) {
                const int r0 = w * 24 + q * 8;
                const int row = r0 + srow8;
                const char* src = (const char*)(fn + (size_t)(l0 + row) * CC) + c0 * 2
                                  + ((sch ^ (row & 7)) << 4);
                gll16(src, base + 12288 + r0 * 128);
            }
        }
    };

    stageF(0, 0);
    asm volatile("s_waitcnt vmcnt(0)" ::: "memory");
    __syncthreads();

#pragma unroll 2
    for (int tt = 0; tt < 6; ++tt) {
        if (tt < 5) stageF((tt + 1) & 1, (tt + 1) * 64);   // async prefetch
        const char* abase = lds + (tt & 1) * 24576;
        const char* bbase = diag ? abase : abase + 12288;
#pragma unroll
        for (int ks = 0; ks < 2; ++ks) {
            short8 a[3], bb[3];
#pragma unroll
            for (int im = 0; im < 3; ++im) {
                const int row = wrow * 48 + im * 16 + (lane & 15);
                a[im] = *(const short8*)(abase + row * 128
                         + (((ks * 4 + (lane >> 4)) ^ (row & 7)) << 4));
            }
#pragma unroll
            for (int jn = 0; jn < 3; ++jn) {
                const int row = wcol * 48 + jn * 16 + (lane & 15);
                bb[jn] = *(const short8*)(bbase + row * 128
                         + (((ks * 4 + (lane >> 4)) ^ (row & 7)) << 4));
            }
#pragma unroll
            for (int im = 0; im < 3; ++im)
#pragma unroll
                for (int jn = 0; jn < 3; ++jn)
                    acc[im][jn] = __builtin_amdgcn_mfma_f32_16x16x32_bf16(
                        a[im], bb[jn], acc[im][jn], 0, 0, 0);
        }
        asm volatile("s_waitcnt vmcnt(0)" ::: "memory");
        __syncthreads();
    }

    // ---- epilogue: stage P (s rows) at lds[0..6K), p (l rows) at lds[12288..)
    {
        const char* Pb = (const char*)Ppad + (size_t)(n * LL + s0) * 64;
        const char* pb = (const char*)ppad + (size_t)(n * LL + l0) * 64;
        const int erow = lane >> 2, ech = lane & 3;
#pragma unroll
        for (int q3 = 0; q3 < 3; ++q3) {
            const int q = w * 3 + q3;                 // 0..11 (wave-uniform)
            const int qq = (q < 6) ? q : q - 6;
            const int row = qq * 16 + erow;
            const char* sb = (q < 6) ? Pb : pb;
            gll16(sb + row * 64 + ((ech ^ (row & 3)) << 4),
                  lds + ((q < 6) ? 0 : 12288) + qq * 1024);
        }
    }
    asm volatile("s_waitcnt vmcnt(0)" ::: "memory");
    __syncthreads();

    short8 a2[3], b2[3];
#pragma unroll
    for (int im = 0; im < 3; ++im) {
        const int row = wrow * 48 + im * 16 + (lane & 15);
        a2[im] = *(const short8*)(lds + row * 64 + (((lane >> 4) ^ (row & 3)) << 4));
    }
#pragma unroll
    for (int jn = 0; jn < 3; ++jn) {
        const int row = wcol * 48 + jn * 16 + (lane & 15);
        b2[jn] = *(const short8*)(lds + 12288 + row * 64 + (((lane >> 4) ^ (row & 3)) << 4));
    }

    float pos = 0.f, neg = 0.f, npc = 0.f, nnc = 0.f;
#pragma unroll
    for (int im = 0; im < 3; ++im) {
        const f32x4 sd4 = *(const f32x4*)(selfdot + (size_t)n * LL + s0
                            + wrow * 48 + im * 16 + ((lane >> 4) << 2));
#pragma unroll
        for (int jn = 0; jn < 3; ++jn) {
            f32x4 z = {0.f, 0.f, 0.f, 0.f};
            f32x4 pdv = __builtin_amdgcn_mfma_f32_16x16x32_bf16(a2[im], b2[jn], z, 0, 0, 0);
#pragma unroll
            for (int r = 0; r < 4; ++r) {
                const float fc = acc[im][jn][r] - DINO_SHIFT;
                const float pc = sd4[r] - pdv[r];
                const float v = fc * pc;
                if (fc > 0.f)      { pos += v; npc += 1.f; }
                else if (fc < 0.f) { neg += v; nnc += 1.f; }
            }
        }
    }
    pos *= wgt; neg *= wgt; npc *= wgt; nnc *= wgt;

#pragma unroll
    for (int off = 32; off; off >>= 1) {
        pos += __shfl_xor(pos, off); neg += __shfl_xor(neg, off);
        npc += __shfl_xor(npc, off); nnc += __shfl_xor(nnc, off);
    }
    if (lane == 0) { red[w][0] = pos; red[w][1] = neg; red[w][2] = npc; red[w][3] = nnc; }
    __syncthreads();
    if (tid == 0) {
        partials[b * 4 + 0] = red[0][0] + red[1][0] + red[2][0] + red[3][0];
        partials[b * 4 + 1] = red[0][1] + red[1][1] + red[2][1] + red[3][1];
        partials[b * 4 + 2] = red[0][2] + red[1][2] + red[2][2] + red[3][2];
        partials[b * 4 + 3] = red[0][3] + red[1][3] + red[2][3] + red[3][3];
    }
}

// ---------------------------------------------------------------------------
// Kernel 3: deterministic final reduce
// ---------------------------------------------------------------------------
__global__ void final_kernel(const float* __restrict__ partials,
                             const float* __restrict__ pw,
                             const float* __restrict__ nw,
                             float* __restrict__ out) {
    __shared__ float red[4][4];
    const int tid = threadIdx.x;
    float pos = 0.f, neg = 0.f, np = 0.f, nn = 0.f;
    for (int i = tid; i < NBLK2; i += 256) {
        pos += partials[i * 4 + 0];
        neg += partials[i * 4 + 1];
        np  += partials[i * 4 + 2];
        nn  += partials[i * 4 + 3];
    }
#pragma unroll
    for (int off = 32; off; off >>= 1) {
        pos += __shfl_xor(pos, off); neg += __shfl_xor(neg, off);
        np  += __shfl_xor(np, off);  nn  += __shfl_xor(nn, off);
    }
    const int w = tid >> 6, lane = tid & 63;
    if (lane == 0) { red[w][0] = pos; red[w][1] = neg; red[w][2] = np; red[w][3] = nn; }
    __syncthreads();
    if (tid == 0) {
        pos = red[0][0] + red[1][0] + red[2][0] + red[3][0];
        neg = red[0][1] + red[1][1] + red[2][1] + red[3][1];
        np  = red[0][2] + red[1][2] + red[2][2] + red[3][2];
        nn  = red[0][3] + red[1][3] + red[2][3] + red[3][3];
        out[0] = (pos / np) * pw[0] + (neg / nn) * nw[0];
    }
}

extern "C" void kernel_launch(void* const* d_in, const int* in_sizes, int n_in,
                              void* d_out, int out_size, void* d_ws, size_t ws_size,
                              hipStream_t stream) {
    const float* f  = (const float*)d_in[0];
    const float* p  = (const float*)d_in[1];
    const float* pw = (const float*)d_in[2];
    const float* nw = (const float*)d_in[3];
    float* out = (float*)d_out;

    // ws layout (16B-aligned): fnorm | Ppad | ppad | selfdot | partials  (~4.2 MB)
    unsigned short* fnorm = (unsigned short*)d_ws;                        // N*L*C bf16
    unsigned short* Ppad  = fnorm + (size_t)NN * LL * CC;                 // N*L*32
    unsigned short* ppad  = Ppad + (size_t)NN * LL * 32;                  // N*L*32
    float* selfdot = (float*)(ppad + (size_t)NN * LL * 32);               // N*L
    float* partials = selfdot + (size_t)NN * LL;                          // NBLK2*4

    prep_kernel<<<(NN * LL) / 4, 256, 0, stream>>>(f, p, fnorm, Ppad, ppad, selfdot);
    pair_kernel<<<NBLK2, 256, 0, stream>>>(fnorm, Ppad, ppad, selfdot, partials);
    final_kernel<<<1, 256, 0, stream>>>(partials, pw, nw, out);
}